// Round 1
// baseline (66.014 us; speedup 1.0000x reference)
//
#include <hip/hip_runtime.h>

// CubicalEcc: x [8,3,224,224] f32 -> ecc [8,3,32] f32
// T-construction sublevel: verts/edges take min over incident pixels.
// Strategy: signed first-bin histogram per (b,c), then prefix sum.

#define HH 224
#define WW 224
#define STEPS 32
#define STRIPS 16          // row-strips per image over the 225-row vertex grid
#define ROWS_PER_STRIP 15  // 16*15 = 240 >= 225
#define NBC 24             // 8*3 images
#define VROWS (HH + 1)
#define VCOLS (WW + 1)

// smallest k in [0,32) with v <= t_k, t_k = -2 + k*(4/31); returns 32 if none
__device__ __forceinline__ int bin_of(float v) {
    const float step = 4.0f / 31.0f;
    float u = (v + 2.0f) * (31.0f / 4.0f);  // 31/4 exact in fp32
    int k = (int)ceilf(u);
    k = max(0, min(32, k));
    // fix possible 1-step rounding error, consistent with t_k = -2 + k*step
    if (k > 0) {
        float tkm1 = __fadd_rn(-2.0f, __fmul_rn((float)(k - 1), step));
        if (v <= tkm1) k--;
    }
    if (k < 32) {
        float tk = __fadd_rn(-2.0f, __fmul_rn((float)k, step));
        if (v > tk) k++;
    }
    return k;
}

__global__ __launch_bounds__(256) void ecc_hist(const float* __restrict__ x,
                                                int* __restrict__ ws) {
    __shared__ int whist[4 * STEPS];  // per-wave privatized histograms
    const int tid = threadIdx.x;
    for (int i = tid; i < 4 * STEPS; i += 256) whist[i] = 0;
    __syncthreads();

    const int bid = blockIdx.x;
    const int bc = bid / STRIPS;
    const int s = bid - bc * STRIPS;
    const int r0 = s * ROWS_PER_STRIP;
    const int r1 = min(VROWS, r0 + ROWS_PER_STRIP);
    const int cells = (r1 - r0) * VCOLS;  // may be 0 for last strip
    const float* img = x + (size_t)bc * (HH * WW);
    int* wh = whist + (tid >> 6) * STEPS;
    const float INF = __builtin_huge_valf();

    for (int idx = tid; idx < cells; idx += 256) {
        const int ri = idx / VCOLS;
        const int j = idx - ri * VCOLS;
        const int i = r0 + ri;
        const bool jn = (j < WW), in_ = (i < HH), jp = (j > 0), ip = (i > 0);

        const float p11 = (in_ && jn) ? img[i * WW + j] : INF;
        const float p01 = (ip && jn) ? img[(i - 1) * WW + j] : INF;
        const float p10 = (in_ && jp) ? img[i * WW + (j - 1)] : INF;
        const float p00 = (ip && jp) ? img[(i - 1) * WW + (j - 1)] : INF;

        // cell values (vertex always has >=1 finite incident pixel)
        const float vv = fminf(fminf(p00, p01), fminf(p10, p11));
        int kV = bin_of(vv);                           // +1
        int kH = jn ? bin_of(fminf(p01, p11)) : 99;    // -1 (horiz edge)
        int kW = in_ ? bin_of(fminf(p10, p11)) : 99;   // -1 (vert edge)
        int kF = (in_ && jn) ? bin_of(p11) : 99;       // +1 (face)

        // zero-sum pair cancellation (+1 with -1 at equal bin)
        if (kV == kH)      { kV = 99; kH = 99; }
        else if (kV == kW) { kV = 99; kW = 99; }
        if (kF == kH)      { kF = 99; kH = 99; }
        else if (kF == kW) { kF = 99; kW = 99; }

        if (kV < STEPS) atomicAdd(&wh[kV], 1);
        if (kH < STEPS) atomicAdd(&wh[kH], -1);
        if (kW < STEPS) atomicAdd(&wh[kW], -1);
        if (kF < STEPS) atomicAdd(&wh[kF], 1);
    }
    __syncthreads();

    if (tid < STEPS) {
        ws[bid * STEPS + tid] = whist[tid] + whist[STEPS + tid] +
                                whist[2 * STEPS + tid] + whist[3 * STEPS + tid];
    }
}

__global__ __launch_bounds__(64) void ecc_final(const int* __restrict__ ws,
                                                float* __restrict__ out) {
    __shared__ int tot[STEPS];
    const int bc = blockIdx.x;
    const int tid = threadIdx.x;
    if (tid < STEPS) {
        int s = 0;
        for (int st = 0; st < STRIPS; ++st)
            s += ws[(bc * STRIPS + st) * STEPS + tid];
        tot[tid] = s;
    }
    __syncthreads();
    if (tid < STEPS) {
        int acc = 0;
        for (int j = 0; j <= tid; ++j) acc += tot[j];
        out[bc * STEPS + tid] = (float)acc;
    }
}

extern "C" void kernel_launch(void* const* d_in, const int* in_sizes, int n_in,
                              void* d_out, int out_size, void* d_ws, size_t ws_size,
                              hipStream_t stream) {
    const float* x = (const float*)d_in[0];
    float* out = (float*)d_out;
    int* ws = (int*)d_ws;  // NBC*STRIPS*STEPS*4 = 49152 bytes

    ecc_hist<<<NBC * STRIPS, 256, 0, stream>>>(x, ws);
    ecc_final<<<NBC, 64, 0, stream>>>(ws, out);
}

// Round 2
// 59.545 us; speedup vs baseline: 1.1086x; 1.1086x over previous
//
#include <hip/hip_runtime.h>

// CubicalEcc: x [8,3,224,224] f32 -> ecc [8,3,32] f32
// Signed first-bin histogram per image, then prefix sum.
// Key identity: bin(min(a,b)) = min(bin(a),bin(b)) (bin_of monotone), so we
// bin PIXELS once and derive all cell bins with integer mins. Invalid
// (out-of-image) pixels get bin=64, which auto-handles all borders.

#define HH 224
#define WW 224
#define STEPS 32
#define NBC 24     // 8*3 images
#define VROWS 225
#define RBLK 57    // row-groups per image: 57*4 = 228 >= 225 vertex rows

// smallest k in [0,32) with v <= t_k, t_k = -2 + k*(4/31); >=32 => never counted
__device__ __forceinline__ int bin_of(float v) {
    int k = (int)ceilf(fmaf(v, 7.75f, 15.5f));  // (v+2)*31/4
    return max(0, min(32, k));
}

__global__ __launch_bounds__(256) void ecc_hist(const float* __restrict__ x,
                                                int* __restrict__ ws) {
    __shared__ int whist[4 * STEPS];  // one 32-bin hist per wave
    const int tid = threadIdx.x;
    if (tid < 4 * STEPS) whist[tid] = 0;
    __syncthreads();

    const int qc = tid & 63;          // quad-column: covers vertex cols 4*qc..4*qc+3
    const int r = tid >> 6;           // wave index == row within this block's group
    const int i = blockIdx.x * 4 + r; // vertex row
    const int bc = blockIdx.y;        // image index
    const float* img = x + (size_t)bc * (HH * WW);
    int* wh = whist + r * STEPS;
    const int j0 = qc * 4;

    if (qc <= 56 && i < VROWS) {
        // binsA: pixel row i-1, cols j0-1..j0+3 ; binsB: pixel row i, same cols
        int binsA[5], binsB[5];
        #pragma unroll
        for (int c = 0; c < 5; ++c) { binsA[c] = 64; binsB[c] = 64; }
        const bool rA = (i >= 1), rB = (i < HH);

        if (j0 + 3 < WW) {  // fast path: cols j0..j0+3 all valid pixels
            if (rA) {
                const float4 va = *(const float4*)&img[(i - 1) * WW + j0];
                binsA[1] = bin_of(va.x); binsA[2] = bin_of(va.y);
                binsA[3] = bin_of(va.z); binsA[4] = bin_of(va.w);
                if (j0 > 0) binsA[0] = bin_of(img[(i - 1) * WW + j0 - 1]);
            }
            if (rB) {
                const float4 vb = *(const float4*)&img[i * WW + j0];
                binsB[1] = bin_of(vb.x); binsB[2] = bin_of(vb.y);
                binsB[3] = bin_of(vb.z); binsB[4] = bin_of(vb.w);
                if (j0 > 0) binsB[0] = bin_of(img[i * WW + j0 - 1]);
            }
        } else {  // boundary quad (j0 = 224): only col 223 exists
            #pragma unroll
            for (int c = 0; c < 5; ++c) {
                const int j = j0 - 1 + c;
                if (j >= 0 && j < WW) {
                    if (rA) binsA[c] = bin_of(img[(i - 1) * WW + j]);
                    if (rB) binsB[c] = bin_of(img[i * WW + j]);
                }
            }
        }

        #pragma unroll
        for (int c = 0; c < 4; ++c) {
            const int b00 = binsA[c], b01 = binsA[c + 1];
            const int b10 = binsB[c], b11 = binsB[c + 1];
            int kH = min(b01, b11);                    // -1 (horizontal edge)
            int kW = min(b10, b11);                    // -1 (vertical edge)
            int kV = min(min(b00, b01), min(b10, b11)); // +1 (vertex)
            int kF = b11;                              // +1 (face)
            // zero-sum pair cancellation
            if (kV == kH)      { kV = 64; kH = 64; }
            else if (kV == kW) { kV = 64; kW = 64; }
            if (kF == kH)      { kF = 64; kH = 64; }
            else if (kF == kW) { kF = 64; kW = 64; }
            if (kV < STEPS) atomicAdd(&wh[kV], 1);
            if (kH < STEPS) atomicAdd(&wh[kH], -1);
            if (kW < STEPS) atomicAdd(&wh[kW], -1);
            if (kF < STEPS) atomicAdd(&wh[kF], 1);
        }
    }
    __syncthreads();

    if (tid < STEPS) {
        const int bid = blockIdx.y * RBLK + blockIdx.x;
        ws[bid * STEPS + tid] = whist[tid] + whist[STEPS + tid] +
                                whist[2 * STEPS + tid] + whist[3 * STEPS + tid];
    }
}

__global__ __launch_bounds__(64) void ecc_final(const int* __restrict__ ws,
                                                float* __restrict__ out) {
    __shared__ int tot[STEPS];
    const int bc = blockIdx.x;
    const int tid = threadIdx.x;
    if (tid < STEPS) {
        int s = 0;
        for (int st = 0; st < RBLK; ++st)
            s += ws[(bc * RBLK + st) * STEPS + tid];
        tot[tid] = s;
    }
    __syncthreads();
    if (tid < STEPS) {
        int acc = 0;
        for (int j = 0; j <= tid; ++j) acc += tot[j];
        out[bc * STEPS + tid] = (float)acc;
    }
}

extern "C" void kernel_launch(void* const* d_in, const int* in_sizes, int n_in,
                              void* d_out, int out_size, void* d_ws, size_t ws_size,
                              hipStream_t stream) {
    const float* x = (const float*)d_in[0];
    float* out = (float*)d_out;
    int* ws = (int*)d_ws;  // 57*24*32*4 = 175104 bytes used

    ecc_hist<<<dim3(RBLK, NBC), 256, 0, stream>>>(x, ws);
    ecc_final<<<NBC, 64, 0, stream>>>(ws, out);
}

// Round 3
// 59.257 us; speedup vs baseline: 1.1140x; 1.0049x over previous
//
#include <hip/hip_runtime.h>

// CubicalEcc: x [8,3,224,224] f32 -> ecc [8,3,32] f32
// Per-pixel Euler increment: every cell (vertex/edge/face) is attributed to
// its unique owning pixel (argmin over incident pixels, ties by memory order).
// chi(t) = sum_p [v_p <= t] * delta_p,  delta_p = 1 + nV(p) - nE(p),
// where nE = # incident edges p owns (beats the 1 neighbor across the edge),
// nV = # incident vertices p owns (beats all 3 other incident pixels).
// "p beats q": v_p < v_q if q earlier in row-major order, v_p <= v_q if later.
// Out-of-image neighbors are +inf (never win). Exact, including ties.
// One signed histogram update per pixel (skipped when delta==0), prefix-sum.

#define HH 224
#define WW 224
#define STEPS 32
#define NBC 24     // 8*3 images
#define RBLK 56    // blocks per image; each covers 4 pixel rows

// smallest k in [0,32) with v <= t_k, t_k = -2 + k*(4/31); 32 => never counted
__device__ __forceinline__ int bin_of(float v) {
    int k = (int)ceilf(fmaf(v, 7.75f, 15.5f));  // (v+2)*31/4
    return max(0, min(32, k));
}

__global__ __launch_bounds__(256) void ecc_hist(const float* __restrict__ x,
                                                int* __restrict__ ws) {
    __shared__ int whist[4 * STEPS];  // one 32-bin hist per wave
    const int tid = threadIdx.x;
    if (tid < 4 * STEPS) whist[tid] = 0;
    __syncthreads();

    const int lane = tid & 63;
    const int r = tid >> 6;
    const int i = blockIdx.x * 4 + r;  // pixel row, always < 224
    const int bc = blockIdx.y;
    const float* img = x + (size_t)bc * (HH * WW);
    int* wh = whist + r * STEPS;
    const float INF = __builtin_huge_valf();

    if (lane < 56) {
        const int j0 = lane * 4;  // this thread: pixels (i, j0..j0+3)
        const float* rowC = img + i * WW;
        const float4 c4 = *(const float4*)(rowC + j0);
        const float cL = (j0 > 0) ? rowC[j0 - 1] : INF;
        const float cR = (j0 + 4 < WW) ? rowC[j0 + 4] : INF;
        float4 m4 = make_float4(INF, INF, INF, INF);
        float mL = INF, mR = INF;
        if (i > 0) {
            const float* rowM = rowC - WW;
            m4 = *(const float4*)(rowM + j0);
            mL = (j0 > 0) ? rowM[j0 - 1] : INF;
            mR = (j0 + 4 < WW) ? rowM[j0 + 4] : INF;
        }
        float4 p4 = make_float4(INF, INF, INF, INF);
        float pL = INF, pR = INF;
        if (i + 1 < HH) {
            const float* rowP = rowC + WW;
            p4 = *(const float4*)(rowP + j0);
            pL = (j0 > 0) ? rowP[j0 - 1] : INF;
            pR = (j0 + 4 < WW) ? rowP[j0 + 4] : INF;
        }

        const float cm[6] = {cL, c4.x, c4.y, c4.z, c4.w, cR};
        const float mm[6] = {mL, m4.x, m4.y, m4.z, m4.w, mR};
        const float pm[6] = {pL, p4.x, p4.y, p4.z, p4.w, pR};

        #pragma unroll
        for (int c = 0; c < 4; ++c) {
            const float v = cm[c + 1];
            // earlier neighbors (strict <): UL, U, UR, L
            const bool bUL = v < mm[c];
            const bool bU  = v < mm[c + 1];
            const bool bUR = v < mm[c + 2];
            const bool bL  = v < cm[c];
            // later neighbors (<=): R, DL, D, DR
            const bool bR  = v <= cm[c + 2];
            const bool bDL = v <= pm[c];
            const bool bD  = v <= pm[c + 1];
            const bool bDR = v <= pm[c + 2];
            const int nE = (int)bU + (int)bL + (int)bR + (int)bD;
            const int nV = (int)(bUL & bU & bL) + (int)(bU & bUR & bR) +
                           (int)(bL & bDL & bD) + (int)(bR & bD & bDR);
            const int d = 1 + nV - nE;
            const int k = bin_of(v);
            if (d != 0 && k < STEPS) atomicAdd(&wh[k], d);
        }
    }
    __syncthreads();

    if (tid < STEPS) {
        ws[((size_t)bc * RBLK + blockIdx.x) * STEPS + tid] =
            whist[tid] + whist[STEPS + tid] +
            whist[2 * STEPS + tid] + whist[3 * STEPS + tid];
    }
}

__global__ __launch_bounds__(64) void ecc_final(const int* __restrict__ ws,
                                                float* __restrict__ out) {
    __shared__ int part[2][STEPS];
    const int bc = blockIdx.x;
    const int tid = threadIdx.x;
    const int bin = tid & 31;
    const int half = tid >> 5;
    {
        int s = 0;
        for (int st = half * 28; st < half * 28 + 28; ++st)
            s += ws[((size_t)bc * RBLK + st) * STEPS + bin];
        part[half][bin] = s;
    }
    __syncthreads();
    if (tid < STEPS) {
        int acc = 0;
        for (int j = 0; j <= tid; ++j) acc += part[0][j] + part[1][j];
        out[bc * STEPS + tid] = (float)acc;
    }
}

extern "C" void kernel_launch(void* const* d_in, const int* in_sizes, int n_in,
                              void* d_out, int out_size, void* d_ws, size_t ws_size,
                              hipStream_t stream) {
    const float* x = (const float*)d_in[0];
    float* out = (float*)d_out;
    int* ws = (int*)d_ws;  // 24*56*32*4 = 172032 bytes used

    ecc_hist<<<dim3(RBLK, NBC), 256, 0, stream>>>(x, ws);
    ecc_final<<<NBC, 64, 0, stream>>>(ws, out);
}